// Round 10
// baseline (180.636 us; speedup 1.0000x reference)
//
#include <hip/hip_runtime.h>

#define D_MODEL 768
#define N_HEADS 12
#define DK      64
#define BB      2
#define SS      2048
#define PH      (BB*SS*D_MODEL)      // 3,145,728 elems
#define WN      (D_MODEL*D_MODEL)    // 589,824 elems

typedef short bf8_t   __attribute__((ext_vector_type(8)));   // 8 x bf16 bits
typedef float f32x4   __attribute__((ext_vector_type(4)));

// f32 -> bf16 bits, round-to-nearest-even (finite inputs)
__device__ __forceinline__ unsigned short f2b(float f) {
  unsigned u = __builtin_bit_cast(unsigned, f);
  unsigned r = (u + 0x7FFFu + ((u >> 16) & 1u)) >> 16;
  return (unsigned short)r;
}
__device__ __forceinline__ unsigned pk2(float a, float b) {
  return (unsigned)f2b(a) | ((unsigned)f2b(b) << 16);
}
__device__ __forceinline__ f32x4 mfma16(bf8_t a, bf8_t b, f32x4 c) {
  return __builtin_amdgcn_mfma_f32_16x16x32_bf16(a, b, c, 0, 0, 0);
}

// Load one 16x32 fragment from a swizzled 64-wide bf16 LDS tile.
// lane: row = rbase + (lane&15), k = kk*32 + (lane>>4)*8 + j (j=0..7)
__device__ __forceinline__ bf8_t ld_frag64(const unsigned short* t, int rbase, int kk, int lane) {
  int row = rbase + (lane & 15);
  int k = (kk << 5) + ((lane >> 4) << 3);
  uint4 u = *(const uint4*)&t[(row << 6) + (k ^ ((row & 7) << 3))];
  return __builtin_bit_cast(bf8_t, u);
}

// Write a thread's two 16B chunks (rows r0 and r0+32, k-chunk k8) swizzled.
__device__ __forceinline__ void st_tile_pair(unsigned short* lds, int r0, int k8, uint4 a0, uint4 a1) {
  int sw = ((k8 ^ (r0 & 7)) << 3);
  *(uint4*)&lds[(r0 << 6) + sw] = a0;
  *(uint4*)&lds[((r0 + 32) << 6) + sw] = a1;     // (r0+32)&7 == r0&7
}

__device__ __forceinline__ void mma_step(const unsigned short* As, const unsigned short* Ws,
                                         int w, int lane, f32x4 acc[4]) {
#pragma unroll
  for (int kk = 0; kk < 2; ++kk) {
    bf8_t a = ld_frag64(As, w << 4, kk, lane);
#pragma unroll
    for (int n = 0; n < 4; ++n)
      acc[n] = mfma16(a, ld_frag64(Ws, n << 4, kk, lane), acc[n]);
  }
}

// ---------------------------------------------------------------------------
// prep: convert q,k,v (3 x PH f32) and wq,wk,wv,wo (4 x WN f32) to bf16 into
// one contiguous dst region, in that order.  Chunk = 8 elems.
// ---------------------------------------------------------------------------
__global__ __launch_bounds__(256)
void prep(const float* __restrict__ q, const float* __restrict__ k, const float* __restrict__ v,
          const float* __restrict__ wq, const float* __restrict__ wk,
          const float* __restrict__ wv, const float* __restrict__ wo,
          unsigned short* __restrict__ dst) {
  const int QKV_C = PH / 8;           // 393216
  const int W_C   = WN / 8;           // 73728
  const int TOTAL = 3 * QKV_C + 4 * W_C;
  for (int c = blockIdx.x * 256 + threadIdx.x; c < TOTAL; c += gridDim.x * 256) {
    const float* s;
    int off;
    if (c < 3 * QKV_C) {
      int seg = c / QKV_C; off = c - seg * QKV_C;
      s = seg == 0 ? q : seg == 1 ? k : v;
    } else {
      int c2 = c - 3 * QKV_C;
      int seg = c2 / W_C; off = c2 - seg * W_C;
      s = seg == 0 ? wq : seg == 1 ? wk : seg == 2 ? wv : wo;
    }
    const float* p = s + (size_t)off * 8;
    float4 a = *(const float4*)p;
    float4 b = *(const float4*)(p + 4);
    uint4 o;
    o.x = pk2(a.x, a.y); o.y = pk2(a.z, a.w);
    o.z = pk2(b.x, b.y); o.w = pk2(b.z, b.w);
    *(uint4*)&dst[(size_t)c * 8] = o;
  }
}

// ---------------------------------------------------------------------------
// Fused QKV projection (bf16 in, bf16 out).  Grid 2304, 1D, XCD-chunked.
// z=0: Q -> [B,H,S,dk] * 0.125 ; z=1: K -> [B,H,S,dk] ; z=2: V -> [B,H,dk,S].
// ---------------------------------------------------------------------------
__global__ __launch_bounds__(256)
void qkv_proj(const unsigned short* __restrict__ Qc, const unsigned short* __restrict__ Kc,
              const unsigned short* __restrict__ Vc,
              const unsigned short* __restrict__ Wq, const unsigned short* __restrict__ Wk,
              const unsigned short* __restrict__ Wv,
              const float* __restrict__ bq, const float* __restrict__ bk,
              const float* __restrict__ bv,
              unsigned short* __restrict__ Qh, unsigned short* __restrict__ Kh,
              unsigned short* __restrict__ VT) {
  __shared__ __align__(16) unsigned short As[4096];
  __shared__ __align__(16) unsigned short Ws[4096];
  const int tid = threadIdx.x, lane = tid & 63, w = tid >> 6;
  const int g = lane >> 4, qc = lane & 15;
  const int p = blockIdx.x;
  const int l = (p & 7) * 288 + (p >> 3);
  const int z = l / 768, rr = l % 768;
  const int m0 = (rr / 12) << 6, n0 = (rr % 12) << 6;

  const unsigned short* A = z == 0 ? Qc : z == 1 ? Kc : Vc;
  const unsigned short* W = z == 0 ? Wq : z == 1 ? Wk : Wv;
  const float* bias = z == 0 ? bq : z == 1 ? bk : bv;
  const float oscale = z == 0 ? 0.125f : 1.0f;

  const int r0 = tid >> 3, k8 = tid & 7;
  const unsigned short* Ab0 = A + (size_t)(m0 + r0) * D_MODEL + (k8 << 3);
  const unsigned short* Ab1 = Ab0 + 32 * D_MODEL;
  const unsigned short* Wb0 = W + (size_t)(n0 + r0) * D_MODEL + (k8 << 3);
  const unsigned short* Wb1 = Wb0 + 32 * D_MODEL;

  uint4 ra0 = *(const uint4*)Ab0, ra1 = *(const uint4*)Ab1;
  uint4 rw0 = *(const uint4*)Wb0, rw1 = *(const uint4*)Wb1;

  f32x4 acc[4] = {};
  for (int kt = 0; kt < 12; ++kt) {
    __syncthreads();
    st_tile_pair(As, r0, k8, ra0, ra1);
    st_tile_pair(Ws, r0, k8, rw0, rw1);
    __syncthreads();
    if (kt < 11) {
      int off = (kt + 1) << 6;
      ra0 = *(const uint4*)(Ab0 + off); ra1 = *(const uint4*)(Ab1 + off);
      rw0 = *(const uint4*)(Wb0 + off); rw1 = *(const uint4*)(Wb1 + off);
    }
    mma_step(As, Ws, w, lane, acc);
  }

  const int wrow = (w << 4) + (g << 2);
  const int b = m0 >> 11;
  const int h = n0 >> 6;
  if (z < 2) {
    unsigned short* dst = (z == 0 ? Qh : Kh) + ((size_t)(b * N_HEADS + h)) * SS * DK;
#pragma unroll
    for (int n = 0; n < 4; ++n) {
      int col = (n << 4) + qc;
      float bb = bias[n0 + col];
#pragma unroll
      for (int r = 0; r < 4; ++r) {
        int s = (m0 + wrow + r) & (SS - 1);
        dst[(size_t)s * DK + col] = f2b((acc[n][r] + bb) * oscale);
      }
    }
  } else {
    unsigned short* dst = VT + ((size_t)(b * N_HEADS + h)) * DK * SS;
#pragma unroll
    for (int n = 0; n < 4; ++n) {
      int col = (n << 4) + qc;        // d index
      float bb = bias[n0 + col];
      int s = (m0 + wrow) & (SS - 1);
      ushort4 pk;
      pk.x = f2b(acc[n][0] + bb); pk.y = f2b(acc[n][1] + bb);
      pk.z = f2b(acc[n][2] + bb); pk.w = f2b(acc[n][3] + bb);
      *(ushort4*)&dst[(size_t)col * SS + s] = pk;
    }
  }
}

// ---------------------------------------------------------------------------
// MFMA causal attention.  S^T = mfma(K,Q), lane owns one q-row.  P is
// redistributed to the PV A-fragment layout IN REGISTERS via __shfl within
// the qc-column (lanes qc, qc+16, qc+32, qc+48) -- no P LDS round-trip, no
// per-tile lgkmcnt(0)/sched_barrier fence.
// Grid 768 1D XCD-chunked: 24 bh x 32 paired q-tiles of 64 rows.
// ---------------------------------------------------------------------------
__global__ __launch_bounds__(256)
void attn6(const unsigned short* __restrict__ Qh, const unsigned short* __restrict__ Kh,
           const unsigned short* __restrict__ VT,
           float* __restrict__ attn, unsigned short* __restrict__ ctx) {
  __shared__ __align__(16) unsigned short Ks[4096];
  __shared__ __align__(16) unsigned short Vts[4096];

  const int tid = threadIdx.x, lane = tid & 63, w = tid >> 6;
  const int g = lane >> 4, qc = lane & 15;
  const int p = blockIdx.x;
  const int l = (p & 7) * 96 + (p >> 3);
  const int bh = l >> 5;
  const int x = l & 31;
  const int qt = (x & 1) ? (31 - (x >> 1)) : (x >> 1);
  const int q0 = qt << 6;
  const int b = bh / N_HEADS, h = bh - b * N_HEADS;

  const unsigned short* Qb = Qh + (size_t)bh * SS * DK;
  const unsigned short* Kb = Kh + (size_t)bh * SS * DK;
  const unsigned short* Vb = VT + (size_t)bh * DK * SS;
  float* attn_b = attn + (size_t)bh * SS * SS;

  // Q fragments straight from global (B-operand for the S^T mfma)
  bf8_t qf0, qf1;
  {
    const unsigned short* qp = &Qb[(size_t)(q0 + (w << 4) + qc) * DK + (g << 3)];
    qf0 = __builtin_bit_cast(bf8_t, *(const uint4*)qp);
    qf1 = __builtin_bit_cast(bf8_t, *(const uint4*)(qp + 32));
  }

  const int r0 = tid >> 3, k8 = tid & 7;
  auto ldK = [&](int t, uint4& a0, uint4& a1) {
    const unsigned short* bse = Kb + ((size_t)t << 12);
    a0 = *(const uint4*)&bse[(r0 << 6) + (k8 << 3)];
    a1 = *(const uint4*)&bse[((r0 + 32) << 6) + (k8 << 3)];
  };
  auto ldV = [&](int t, uint4& a0, uint4& a1) {
    const unsigned short* bse = Vb + (t << 6);
    a0 = *(const uint4*)&bse[(size_t)r0 * SS + (k8 << 3)];
    a1 = *(const uint4*)&bse[(size_t)(r0 + 32) * SS + (k8 << 3)];
  };

  const int qglob = q0 + (w << 4) + qc;   // this lane's q row
  float psum = 0.f;

  // ---------------- pass 1: row sums ----------------
  {
    uint4 ka0, ka1;
    ldK(0, ka0, ka1);
    for (int t = 0; t <= qt; ++t) {
      __syncthreads();
      st_tile_pair(Ks, r0, k8, ka0, ka1);
      __syncthreads();
      if (t < qt) ldK(t + 1, ka0, ka1);
      f32x4 sc[4] = {};
#pragma unroll
      for (int kk = 0; kk < 2; ++kk) {
        bf8_t qf = kk ? qf1 : qf0;
#pragma unroll
        for (int n = 0; n < 4; ++n)
          sc[n] = mfma16(ld_frag64(Ks, n << 4, kk, lane), qf, sc[n]);
      }
      const bool diag = (t == qt);
      const int kbase = (t << 6) + (g << 2);
#pragma unroll
      for (int n = 0; n < 4; ++n) {
#pragma unroll
        for (int r = 0; r < 4; ++r) {
          int k = kbase + (n << 4) + r;
          bool ok = !diag || (k <= qglob);
          psum += ok ? __expf(sc[n][r]) : 0.f;
        }
      }
    }
  }
  // deferred cross-lane reduce: lanes {qc, qc+16, qc+32, qc+48} share one q
  psum += __shfl_xor(psum, 16);
  psum += __shfl_xor(psum, 32);
  const float Linv = 1.0f / psum;

  // ---------------- pass 2: attn write + PV ----------------
  f32x4 ct[4] = {};
  {
    const int srcA = ((g & 1) << 5) + qc;   // lane of g' = 2*(g&1)
    const int srcB = srcA + 16;             // lane of g' = 2*(g&1)+1
    const bool hi = (g >> 1) != 0;          // selects block n = 2kk+1

    uint4 ka0, ka1, va0, va1;
    ldK(0, ka0, ka1);
    ldV(0, va0, va1);
    for (int t = 0; t <= qt; ++t) {
      __syncthreads();
      st_tile_pair(Ks, r0, k8, ka0, ka1);
      st_tile_pair(Vts, r0, k8, va0, va1);
      __syncthreads();
      if (t < qt) { ldK(t + 1, ka0, ka1); ldV(t + 1, va0, va1); }
      f32x4 sc[4] = {};
#pragma unroll
      for (int kk = 0; kk < 2; ++kk) {
        bf8_t qf = kk ? qf1 : qf0;
#pragma unroll
        for (int n = 0; n < 4; ++n)
          sc[n] = mfma16(ld_frag64(Ks, n << 4, kk, lane), qf, sc[n]);
      }
      const bool diag = (t == qt);
      const int k0 = t << 6;
      // normalize, store attn, pack P (own coords: P[qc][16n+4g+r])
      unsigned u0[4], u1[4];
#pragma unroll
      for (int n = 0; n < 4; ++n) {
        int klocal = (n << 4) + (g << 2);
        int kb = k0 + klocal;
        float pr[4];
#pragma unroll
        for (int r = 0; r < 4; ++r) {
          bool ok = !diag || (kb + r <= qglob);
          pr[r] = ok ? __expf(sc[n][r]) * Linv : 0.f;
        }
        float4 pv;
        pv.x = pr[0]; pv.y = pr[1]; pv.z = pr[2]; pv.w = pr[3];
        *(float4*)&attn_b[(size_t)qglob * SS + kb] = pv;
        u0[n] = pk2(pr[0], pr[1]);
        u1[n] = pk2(pr[2], pr[3]);
      }
      // redistribute P to PV A-fragment layout in registers:
      // frag[kk] word w <- u[w&1][n=2kk+(g>>1)] from lane g'=2(g&1)+(w>>1)
#pragma unroll
      for (int kk = 0; kk < 2; ++kk) {
        unsigned a0 = __shfl(u0[2 * kk], srcA), b0 = __shfl(u0[2 * kk + 1], srcA);
        unsigned a1 = __shfl(u1[2 * kk], srcA), b1 = __shfl(u1[2 * kk + 1], srcA);
        unsigned a2 = __shfl(u0[2 * kk], srcB), b2 = __shfl(u0[2 * kk + 1], srcB);
        unsigned a3 = __shfl(u1[2 * kk], srcB), b3 = __shfl(u1[2 * kk + 1], srcB);
        uint4 pw;
        pw.x = hi ? b0 : a0;
        pw.y = hi ? b1 : a1;
        pw.z = hi ? b2 : a2;
        pw.w = hi ? b3 : a3;
        bf8_t pf = __builtin_bit_cast(bf8_t, pw);
#pragma unroll
        for (int n = 0; n < 4; ++n)
          ct[n] = mfma16(pf, ld_frag64(Vts, n << 4, kk, lane), ct[n]);
      }
    }
  }

  // zero-fill masked upper-triangular tiles (coalesced float4)
  {
    const int zr = tid >> 4;
    const int zc = (tid & 15) << 2;
    const float4 z4 = {0.f, 0.f, 0.f, 0.f};
    for (int c0 = q0 + 64; c0 < SS; c0 += 64) {
#pragma unroll
      for (int i = 0; i < 4; ++i)
        *(float4*)&attn_b[(size_t)(q0 + zr + (i << 4)) * SS + c0 + zc] = z4;
    }
  }

  // ctx (bf16) as [B, S, H*dk];  PV C-layout: row=qlocal=(g<<2)+r, col=d=(n<<4)+qc
  const int wrow = (w << 4) + (g << 2);
#pragma unroll
  for (int n = 0; n < 4; ++n) {
#pragma unroll
    for (int r = 0; r < 4; ++r) {
      int m = q0 + wrow + r;
      int col = (n << 4) + qc;
      ctx[((size_t)(b * SS + m)) * D_MODEL + h * DK + col] = f2b(ct[n][r]);
    }
  }
}

// ---------------------------------------------------------------------------
// Output projection: bf16 A [4096][768] @ bf16 Wo^T + bo -> f32.  64x64 tile.
// ---------------------------------------------------------------------------
__global__ __launch_bounds__(256)
void out_proj(const unsigned short* __restrict__ A, const unsigned short* __restrict__ W,
              const float* __restrict__ bias, float* __restrict__ out) {
  __shared__ __align__(16) unsigned short As[4096];
  __shared__ __align__(16) unsigned short Ws[4096];
  const int tid = threadIdx.x, lane = tid & 63, w = tid >> 6;
  const int g = lane >> 4, qc = lane & 15;
  const int p = blockIdx.x;
  const int l = (p & 7) * 96 + (p >> 3);
  const int m0 = (l / 12) << 6, n0 = (l % 12) << 6;

  const int r0 = tid >> 3, k8 = tid & 7;
  const unsigned short* Ab0 = A + (size_t)(m0 + r0) * D_MODEL + (k8 << 3);
  const unsigned short* Ab1 = Ab0 + 32 * D_MODEL;
  const unsigned short* Wb0 = W + (size_t)(n0 + r0) * D_MODEL + (k8 << 3);
  const unsigned short* Wb1 = Wb0 + 32 * D_MODEL;

  uint4 ra0 = *(const uint4*)Ab0, ra1 = *(const uint4*)Ab1;
  uint4 rw0 = *(const uint4*)Wb0, rw1 = *(const uint4*)Wb1;

  f32x4 acc[4] = {};
  for (int kt = 0; kt < 12; ++kt) {
    __syncthreads();
    st_tile_pair(As, r0, k8, ra0, ra1);
    st_tile_pair(Ws, r0, k8, rw0, rw1);
    __syncthreads();
    if (kt < 11) {
      int off = (kt + 1) << 6;
      ra0 = *(const uint4*)(Ab0 + off); ra1 = *(const uint4*)(Ab1 + off);
      rw0 = *(const uint4*)(Wb0 + off); rw1 = *(const uint4*)(Wb1 + off);
    }
    mma_step(As, Ws, w, lane, acc);
  }

  const int wrow = (w << 4) + (g << 2);
#pragma unroll
  for (int n = 0; n < 4; ++n) {
    int col = n0 + (n << 4) + qc;
    float bb = bias[col];
#pragma unroll
    for (int r = 0; r < 4; ++r)
      out[(size_t)(m0 + wrow + r) * D_MODEL + col] = acc[n][r] + bb;
  }
}

// ---------------------------------------------------------------------------
extern "C" void kernel_launch(void* const* d_in, const int* in_sizes, int n_in,
                              void* d_out, int out_size, void* d_ws, size_t ws_size,
                              hipStream_t stream) {
  const float* q  = (const float*)d_in[0];
  const float* k  = (const float*)d_in[1];
  const float* v  = (const float*)d_in[2];
  // d_in[3] = mask (int32 tril; causal structure exploited directly)
  const float* wq = (const float*)d_in[4];
  const float* bq = (const float*)d_in[5];
  const float* wk = (const float*)d_in[6];
  const float* bk = (const float*)d_in[7];
  const float* wv = (const float*)d_in[8];
  const float* bv = (const float*)d_in[9];
  const float* wo = (const float*)d_in[10];
  const float* bo = (const float*)d_in[11];

  float* out  = (float*)d_out;                    // [B*S, 768]
  float* attn = out + (size_t)BB * SS * D_MODEL;  // [B*H, S, S]

  unsigned short* wsu = (unsigned short*)d_ws;
  unsigned short* Qc  = wsu;
  unsigned short* Kc  = Qc + PH;
  unsigned short* Vc  = Kc + PH;
  unsigned short* Wqb = Vc + PH;
  unsigned short* Wkb = Wqb + WN;
  unsigned short* Wvb = Wkb + WN;
  unsigned short* Wob = Wvb + WN;
  unsigned short* Qhd = Wob + WN;                 // [B,H,S,dk]
  unsigned short* Khd = Qhd + PH;
  unsigned short* VTw = Khd + PH;                 // [B,H,dk,S]
  unsigned short* Cw  = VTw + PH;                 // [B,S,768]

  dim3 blk(256);
  prep<<<2048, blk, 0, stream>>>(q, k, v, wq, wk, wv, wo, wsu);
  qkv_proj<<<2304, blk, 0, stream>>>(Qc, Kc, Vc, Wqb, Wkb, Wvb, bq, bk, bv, Qhd, Khd, VTw);
  attn6<<<768, blk, 0, stream>>>(Qhd, Khd, VTw, attn, Cw);
  out_proj<<<768, blk, 0, stream>>>(Cw, Wob, bo, out);
}

// Round 11
// 176.383 us; speedup vs baseline: 1.0241x; 1.0241x over previous
//
#include <hip/hip_runtime.h>

#define D_MODEL 768
#define N_HEADS 12
#define DK      64
#define BB      2
#define SS      2048
#define PH      (BB*SS*D_MODEL)      // 3,145,728 elems
#define WN      (D_MODEL*D_MODEL)    // 589,824 elems

typedef short bf8_t   __attribute__((ext_vector_type(8)));   // 8 x bf16 bits
typedef float f32x4   __attribute__((ext_vector_type(4)));

typedef __attribute__((address_space(1))) const unsigned int gas_u32;
typedef __attribute__((address_space(3))) unsigned int las_u32;

// f32 -> bf16 bits, round-to-nearest-even (finite inputs)
__device__ __forceinline__ unsigned short f2b(float f) {
  unsigned u = __builtin_bit_cast(unsigned, f);
  unsigned r = (u + 0x7FFFu + ((u >> 16) & 1u)) >> 16;
  return (unsigned short)r;
}
__device__ __forceinline__ unsigned pk2(float a, float b) {
  return (unsigned)f2b(a) | ((unsigned)f2b(b) << 16);
}
__device__ __forceinline__ f32x4 mfma16(bf8_t a, bf8_t b, f32x4 c) {
  return __builtin_amdgcn_mfma_f32_16x16x32_bf16(a, b, c, 0, 0, 0);
}

// Load one 16x32 fragment from a swizzled 64-wide bf16 LDS tile.
// lane: row = rbase + (lane&15), k = kk*32 + (lane>>4)*8 + j (j=0..7)
__device__ __forceinline__ bf8_t ld_frag64(const unsigned short* t, int rbase, int kk, int lane) {
  int row = rbase + (lane & 15);
  int k = (kk << 5) + ((lane >> 4) << 3);
  uint4 u = *(const uint4*)&t[(row << 6) + (k ^ ((row & 7) << 3))];
  return __builtin_bit_cast(bf8_t, u);
}

// Write a thread's two 16B chunks (rows r0 and r0+32, k-chunk k8) swizzled.
__device__ __forceinline__ void st_tile_pair(unsigned short* lds, int r0, int k8, uint4 a0, uint4 a1) {
  int sw = ((k8 ^ (r0 & 7)) << 3);
  *(uint4*)&lds[(r0 << 6) + sw] = a0;
  *(uint4*)&lds[((r0 + 32) << 6) + sw] = a1;     // (r0+32)&7 == r0&7
}

// ---------------------------------------------------------------------------
// global_load_lds staging of one 64x64 bf16 tile into the SAME swizzled LDS
// image st_tile_pair produces (rule #21: linear LDS dest + pre-swizzled
// global source).  Wave w, instr i: HW writes lds_base + lane*16; lane l's
// slot is (row = 16w+8i+l/8, chunk_sw = l&7), whose source chunk is
// (l&7)^(l/8) of that row.  2 instrs/wave = 1 tile per 4-wave block.
// ---------------------------------------------------------------------------
__device__ __forceinline__ void stage_gl(const unsigned short* gsrc,  // tile base (row 0, k 0)
                                         int row_stride,              // elements per row
                                         unsigned short* lds, int w, int lane) {
#pragma unroll
  for (int i = 0; i < 2; ++i) {
    int row = (w << 4) + (i << 3) + (lane >> 3);
    int kc = (lane & 7) ^ (lane >> 3);
    const unsigned short* g = gsrc + (size_t)row * row_stride + (kc << 3);
    las_u32* l = (las_u32*)(lds + (w << 10) + (i << 9));   // wave-uniform base
    __builtin_amdgcn_global_load_lds((gas_u32*)g, l, 16, 0, 0);
  }
}

__device__ __forceinline__ void mma_step(const unsigned short* As, const unsigned short* Ws,
                                         int w, int lane, f32x4 acc[4]) {
#pragma unroll
  for (int kk = 0; kk < 2; ++kk) {
    bf8_t a = ld_frag64(As, w << 4, kk, lane);
#pragma unroll
    for (int n = 0; n < 4; ++n)
      acc[n] = mfma16(a, ld_frag64(Ws, n << 4, kk, lane), acc[n]);
  }
}

// ---------------------------------------------------------------------------
// prep: convert q,k,v (3 x PH f32) and wq,wk,wv,wo (4 x WN f32) to bf16 into
// one contiguous dst region, in that order.  Chunk = 8 elems.
// ---------------------------------------------------------------------------
__global__ __launch_bounds__(256)
void prep(const float* __restrict__ q, const float* __restrict__ k, const float* __restrict__ v,
          const float* __restrict__ wq, const float* __restrict__ wk,
          const float* __restrict__ wv, const float* __restrict__ wo,
          unsigned short* __restrict__ dst) {
  const int QKV_C = PH / 8;           // 393216
  const int W_C   = WN / 8;           // 73728
  const int TOTAL = 3 * QKV_C + 4 * W_C;
  for (int c = blockIdx.x * 256 + threadIdx.x; c < TOTAL; c += gridDim.x * 256) {
    const float* s;
    int off;
    if (c < 3 * QKV_C) {
      int seg = c / QKV_C; off = c - seg * QKV_C;
      s = seg == 0 ? q : seg == 1 ? k : v;
    } else {
      int c2 = c - 3 * QKV_C;
      int seg = c2 / W_C; off = c2 - seg * W_C;
      s = seg == 0 ? wq : seg == 1 ? wk : seg == 2 ? wv : wo;
    }
    const float* p = s + (size_t)off * 8;
    float4 a = *(const float4*)p;
    float4 b = *(const float4*)(p + 4);
    uint4 o;
    o.x = pk2(a.x, a.y); o.y = pk2(a.z, a.w);
    o.z = pk2(b.x, b.y); o.w = pk2(b.z, b.w);
    *(uint4*)&dst[(size_t)c * 8] = o;
  }
}

// ---------------------------------------------------------------------------
// Fused QKV projection (bf16 in, bf16 out).  Grid 2304, 1D, XCD-chunked.
// Staging via global_load_lds (pre-swizzled source, linear LDS dest).
// z=0: Q -> [B,H,S,dk] * 0.125 ; z=1: K -> [B,H,S,dk] ; z=2: V -> [B,H,dk,S].
// ---------------------------------------------------------------------------
__global__ __launch_bounds__(256)
void qkv_proj(const unsigned short* __restrict__ Qc, const unsigned short* __restrict__ Kc,
              const unsigned short* __restrict__ Vc,
              const unsigned short* __restrict__ Wq, const unsigned short* __restrict__ Wk,
              const unsigned short* __restrict__ Wv,
              const float* __restrict__ bq, const float* __restrict__ bk,
              const float* __restrict__ bv,
              unsigned short* __restrict__ Qh, unsigned short* __restrict__ Kh,
              unsigned short* __restrict__ VT) {
  __shared__ __align__(16) unsigned short As[4096];
  __shared__ __align__(16) unsigned short Ws[4096];
  const int tid = threadIdx.x, lane = tid & 63, w = tid >> 6;
  const int g = lane >> 4, qc = lane & 15;
  const int p = blockIdx.x;
  const int l = (p & 7) * 288 + (p >> 3);
  const int z = l / 768, rr = l % 768;
  const int m0 = (rr / 12) << 6, n0 = (rr % 12) << 6;

  const unsigned short* A = z == 0 ? Qc : z == 1 ? Kc : Vc;
  const unsigned short* W = z == 0 ? Wq : z == 1 ? Wk : Wv;
  const float* bias = z == 0 ? bq : z == 1 ? bk : bv;
  const float oscale = z == 0 ? 0.125f : 1.0f;

  const unsigned short* Abase = A + (size_t)m0 * D_MODEL;
  const unsigned short* Wbase = W + (size_t)n0 * D_MODEL;

  f32x4 acc[4] = {};
  for (int kt = 0; kt < 12; ++kt) {
    __syncthreads();                       // readers of previous tile done
    stage_gl(Abase + (kt << 6), D_MODEL, As, w, lane);
    stage_gl(Wbase + (kt << 6), D_MODEL, Ws, w, lane);
    __syncthreads();                       // drains vmcnt -> LDS ready
    mma_step(As, Ws, w, lane, acc);
  }

  const int wrow = (w << 4) + (g << 2);
  const int b = m0 >> 11;
  const int h = n0 >> 6;
  if (z < 2) {
    unsigned short* dst = (z == 0 ? Qh : Kh) + ((size_t)(b * N_HEADS + h)) * SS * DK;
#pragma unroll
    for (int n = 0; n < 4; ++n) {
      int col = (n << 4) + qc;
      float bb = bias[n0 + col];
#pragma unroll
      for (int r = 0; r < 4; ++r) {
        int s = (m0 + wrow + r) & (SS - 1);
        dst[(size_t)s * DK + col] = f2b((acc[n][r] + bb) * oscale);
      }
    }
  } else {
    unsigned short* dst = VT + ((size_t)(b * N_HEADS + h)) * DK * SS;
#pragma unroll
    for (int n = 0; n < 4; ++n) {
      int col = (n << 4) + qc;        // d index
      float bb = bias[n0 + col];
      int s = (m0 + wrow) & (SS - 1);
      ushort4 pk;
      pk.x = f2b(acc[n][0] + bb); pk.y = f2b(acc[n][1] + bb);
      pk.z = f2b(acc[n][2] + bb); pk.w = f2b(acc[n][3] + bb);
      *(ushort4*)&dst[(size_t)col * SS + s] = pk;
    }
  }
}

// ---------------------------------------------------------------------------
// MFMA causal attention (EXACT round-7 attn4, frozen).  S^T = mfma(K,Q),
// lane owns one q-row; P via wave-private LDS + fence; reg-prefetched K/V.
// Grid 768 1D XCD-chunked: 24 bh x 32 paired q-tiles of 64 rows.
// ---------------------------------------------------------------------------
__global__ __launch_bounds__(256)
void attn4(const unsigned short* __restrict__ Qh, const unsigned short* __restrict__ Kh,
           const unsigned short* __restrict__ VT,
           float* __restrict__ attn, unsigned short* __restrict__ ctx) {
  __shared__ __align__(16) unsigned short Ks[4096];
  __shared__ __align__(16) unsigned short Vts[4096];
  __shared__ __align__(16) unsigned short Pw[4][1024];

  const int tid = threadIdx.x, lane = tid & 63, w = tid >> 6;
  const int g = lane >> 4, qc = lane & 15;
  const int p = blockIdx.x;
  const int l = (p & 7) * 96 + (p >> 3);
  const int bh = l >> 5;
  const int x = l & 31;
  const int qt = (x & 1) ? (31 - (x >> 1)) : (x >> 1);
  const int q0 = qt << 6;
  const int b = bh / N_HEADS, h = bh - b * N_HEADS;

  const unsigned short* Qb = Qh + (size_t)bh * SS * DK;
  const unsigned short* Kb = Kh + (size_t)bh * SS * DK;
  const unsigned short* Vb = VT + (size_t)bh * DK * SS;
  float* attn_b = attn + (size_t)bh * SS * SS;

  // Q fragments straight from global (B-operand for the S^T mfma)
  bf8_t qf0, qf1;
  {
    const unsigned short* qp = &Qb[(size_t)(q0 + (w << 4) + qc) * DK + (g << 3)];
    qf0 = __builtin_bit_cast(bf8_t, *(const uint4*)qp);
    qf1 = __builtin_bit_cast(bf8_t, *(const uint4*)(qp + 32));
  }

  const int r0 = tid >> 3, k8 = tid & 7;
  auto ldK = [&](int t, uint4& a0, uint4& a1) {
    const unsigned short* bse = Kb + ((size_t)t << 12);
    a0 = *(const uint4*)&bse[(r0 << 6) + (k8 << 3)];
    a1 = *(const uint4*)&bse[((r0 + 32) << 6) + (k8 << 3)];
  };
  auto ldV = [&](int t, uint4& a0, uint4& a1) {
    const unsigned short* bse = Vb + (t << 6);
    a0 = *(const uint4*)&bse[(size_t)r0 * SS + (k8 << 3)];
    a1 = *(const uint4*)&bse[(size_t)(r0 + 32) * SS + (k8 << 3)];
  };

  const int qglob = q0 + (w << 4) + qc;   // this lane's q row
  float psum = 0.f;

  // ---------------- pass 1: row sums ----------------
  {
    uint4 ka0, ka1;
    ldK(0, ka0, ka1);
    for (int t = 0; t <= qt; ++t) {
      __syncthreads();
      st_tile_pair(Ks, r0, k8, ka0, ka1);
      __syncthreads();
      if (t < qt) ldK(t + 1, ka0, ka1);
      f32x4 sc[4] = {};
#pragma unroll
      for (int kk = 0; kk < 2; ++kk) {
        bf8_t qf = kk ? qf1 : qf0;
#pragma unroll
        for (int n = 0; n < 4; ++n)
          sc[n] = mfma16(ld_frag64(Ks, n << 4, kk, lane), qf, sc[n]);
      }
      const bool diag = (t == qt);
      const int kbase = (t << 6) + (g << 2);
#pragma unroll
      for (int n = 0; n < 4; ++n) {
#pragma unroll
        for (int r = 0; r < 4; ++r) {
          int k = kbase + (n << 4) + r;
          bool ok = !diag || (k <= qglob);
          psum += ok ? __expf(sc[n][r]) : 0.f;
        }
      }
    }
  }
  // deferred cross-lane reduce: lanes {qc, qc+16, qc+32, qc+48} share one q
  psum += __shfl_xor(psum, 16);
  psum += __shfl_xor(psum, 32);
  const float Linv = 1.0f / psum;

  // ---------------- pass 2: attn write + PV ----------------
  f32x4 ct[4] = {};
  unsigned short* myP = Pw[w];
  {
    uint4 ka0, ka1, va0, va1;
    ldK(0, ka0, ka1);
    ldV(0, va0, va1);
    for (int t = 0; t <= qt; ++t) {
      __syncthreads();
      st_tile_pair(Ks, r0, k8, ka0, ka1);
      st_tile_pair(Vts, r0, k8, va0, va1);
      __syncthreads();
      if (t < qt) { ldK(t + 1, ka0, ka1); ldV(t + 1, va0, va1); }
      f32x4 sc[4] = {};
#pragma unroll
      for (int kk = 0; kk < 2; ++kk) {
        bf8_t qf = kk ? qf1 : qf0;
#pragma unroll
        for (int n = 0; n < 4; ++n)
          sc[n] = mfma16(ld_frag64(Ks, n << 4, kk, lane), qf, sc[n]);
      }
      const bool diag = (t == qt);
      const int k0 = t << 6;
#pragma unroll
      for (int n = 0; n < 4; ++n) {
        int klocal = (n << 4) + (g << 2);          // k within tile, 4-aligned
        int kb = k0 + klocal;
        float pr[4];
#pragma unroll
        for (int r = 0; r < 4; ++r) {
          bool ok = !diag || (kb + r <= qglob);
          pr[r] = ok ? __expf(sc[n][r]) * Linv : 0.f;
        }
        float4 pv;
        pv.x = pr[0]; pv.y = pr[1]; pv.z = pr[2]; pv.w = pr[3];
        *(float4*)&attn_b[(size_t)qglob * SS + kb] = pv;
        // P -> wave-private LDS tile [qlocal=16][klocal=64], swizzled
        uint2 pk;
        pk.x = pk2(pr[0], pr[1]);
        pk.y = pk2(pr[2], pr[3]);
        *(uint2*)&myP[(qc << 6) + (klocal ^ ((qc & 7) << 3))] = pk;
      }
      asm volatile("s_waitcnt lgkmcnt(0)" ::: "memory");
      __builtin_amdgcn_sched_barrier(0);
#pragma unroll
      for (int kk = 0; kk < 2; ++kk) {
        bf8_t pf = ld_frag64(myP, 0, kk, lane);
#pragma unroll
        for (int n = 0; n < 4; ++n)
          ct[n] = mfma16(pf, ld_frag64(Vts, n << 4, kk, lane), ct[n]);
      }
    }
  }

  // zero-fill masked upper-triangular tiles (coalesced float4)
  {
    const int zr = tid >> 4;
    const int zc = (tid & 15) << 2;
    const float4 z4 = {0.f, 0.f, 0.f, 0.f};
    for (int c0 = q0 + 64; c0 < SS; c0 += 64) {
#pragma unroll
      for (int i = 0; i < 4; ++i)
        *(float4*)&attn_b[(size_t)(q0 + zr + (i << 4)) * SS + c0 + zc] = z4;
    }
  }

  // ctx (bf16) as [B, S, H*dk];  PV C-layout: row=qlocal=(g<<2)+r, col=d=(n<<4)+qc
  const int wrow = (w << 4) + (g << 2);
#pragma unroll
  for (int n = 0; n < 4; ++n) {
#pragma unroll
    for (int r = 0; r < 4; ++r) {
      int m = q0 + wrow + r;
      int col = (n << 4) + qc;
      ctx[((size_t)(b * SS + m)) * D_MODEL + h * DK + col] = f2b(ct[n][r]);
    }
  }
}

// ---------------------------------------------------------------------------
// Output projection: bf16 A [4096][768] @ bf16 Wo^T + bo -> f32.  64x64 tile,
// global_load_lds staging.
// ---------------------------------------------------------------------------
__global__ __launch_bounds__(256)
void out_proj(const unsigned short* __restrict__ A, const unsigned short* __restrict__ W,
              const float* __restrict__ bias, float* __restrict__ out) {
  __shared__ __align__(16) unsigned short As[4096];
  __shared__ __align__(16) unsigned short Ws[4096];
  const int tid = threadIdx.x, lane = tid & 63, w = tid >> 6;
  const int g = lane >> 4, qc = lane & 15;
  const int p = blockIdx.x;
  const int l = (p & 7) * 96 + (p >> 3);
  const int m0 = (l / 12) << 6, n0 = (l % 12) << 6;

  const unsigned short* Abase = A + (size_t)m0 * D_MODEL;
  const unsigned short* Wbase = W + (size_t)n0 * D_MODEL;

  f32x4 acc[4] = {};
  for (int kt = 0; kt < 12; ++kt) {
    __syncthreads();
    stage_gl(Abase + (kt << 6), D_MODEL, As, w, lane);
    stage_gl(Wbase + (kt << 6), D_MODEL, Ws, w, lane);
    __syncthreads();
    mma_step(As, Ws, w, lane, acc);
  }

  const int wrow = (w << 4) + (g << 2);
#pragma unroll
  for (int n = 0; n < 4; ++n) {
    int col = n0 + (n << 4) + qc;
    float bb = bias[col];
#pragma unroll
    for (int r = 0; r < 4; ++r)
      out[(size_t)(m0 + wrow + r) * D_MODEL + col] = acc[n][r] + bb;
  }
}

// ---------------------------------------------------------------------------
extern "C" void kernel_launch(void* const* d_in, const int* in_sizes, int n_in,
                              void* d_out, int out_size, void* d_ws, size_t ws_size,
                              hipStream_t stream) {
  const float* q  = (const float*)d_in[0];
  const float* k  = (const float*)d_in[1];
  const float* v  = (const float*)d_in[2];
  // d_in[3] = mask (int32 tril; causal structure exploited directly)
  const float* wq = (const float*)d_in[4];
  const float* bq = (const float*)d_in[5];
  const float* wk = (const float*)d_in[6];
  const float* bk = (const float*)d_in[7];
  const float* wv = (const float*)d_in[8];
  const float* bv = (const float*)d_in[9];
  const float* wo = (const float*)d_in[10];
  const float* bo = (const float*)d_in[11];

  float* out  = (float*)d_out;                    // [B*S, 768]
  float* attn = out + (size_t)BB * SS * D_MODEL;  // [B*H, S, S]

  unsigned short* wsu = (unsigned short*)d_ws;
  unsigned short* Qc  = wsu;
  unsigned short* Kc  = Qc + PH;
  unsigned short* Vc  = Kc + PH;
  unsigned short* Wqb = Vc + PH;
  unsigned short* Wkb = Wqb + WN;
  unsigned short* Wvb = Wkb + WN;
  unsigned short* Wob = Wvb + WN;
  unsigned short* Qhd = Wob + WN;                 // [B,H,S,dk]
  unsigned short* Khd = Qhd + PH;
  unsigned short* VTw = Khd + PH;                 // [B,H,dk,S]
  unsigned short* Cw  = VTw + PH;                 // [B,S,768]

  dim3 blk(256);
  prep<<<2048, blk, 0, stream>>>(q, k, v, wq, wk, wv, wo, wsu);
  qkv_proj<<<2304, blk, 0, stream>>>(Qc, Kc, Vc, Wqb, Wkb, Wvb, bq, bk, bv, Qhd, Khd, VTw);
  attn4<<<768, blk, 0, stream>>>(Qhd, Khd, VTw, attn, Cw);
  out_proj<<<768, blk, 0, stream>>>(Cw, Wob, bo, out);
}